// Round 24
// baseline (48.208 us; speedup 1.0000x reference)
//
#include <hip/hip_runtime.h>
#include <hip/hip_bf16.h>

#define S 512
#define HD 384
#define NPAIR 131328   // S*(S+1)/2
#define NOUT 14

typedef __bf16 bf16x8 __attribute__((ext_vector_type(8)));
typedef _Float16 f16x8 __attribute__((ext_vector_type(8)));
typedef float f32x4 __attribute__((ext_vector_type(4)));

__device__ __forceinline__ f32x4 splat4(float v) { return f32x4{v, v, v, v}; }
__device__ __forceinline__ f16x8 splat8h(float v) {
  _Float16 h = (_Float16)v;
  return f16x8{h, h, h, h, h, h, h, h};
}

// tanh poly, deg-5 odd fit (same coeffs since R10). x already f16.
__device__ __forceinline__ f16x8 tanh8_from_x(f16x8 x) {
  f16x8 u = x * x;
  f16x8 p = __builtin_elementwise_fma(u, splat8h(0.065750f), splat8h(-0.303330f));
  p = __builtin_elementwise_fma(u, p, splat8h(0.997245f));
  return x * p;
}

// ---------- transpose tile (f32 [R][C] -> bf16 [C][R]) ----------------------
__device__ __forceinline__ void transp_tile_s(
    float (*t)[33],
    const float* __restrict__ src, __bf16* __restrict__ dst,
    int R, int C, int bx, int by)
{
  const int tx = threadIdx.x & 31, ty = threadIdx.x >> 5;  // 32 x 8
  const int c = bx * 32 + tx;
  #pragma unroll
  for (int p = 0; p < 4; ++p) {
    int r = by * 32 + ty + p * 8;
    t[ty + p * 8][tx] = src[(size_t)r * C + c];
  }
  __syncthreads();
  #pragma unroll
  for (int p = 0; p < 4; ++p) {
    int cc = bx * 32 + ty + p * 8;
    int rr = by * 32 + tx;
    dst[(size_t)cc * R + rr] = (__bf16)t[tx][ty + p * 8];
  }
}

// ---------- prep1: w1 transpose only (the sole gemm1 dependency) ------------
__global__ __launch_bounds__(256) void prep1_kernel(
    const float* __restrict__ w1, __bf16* __restrict__ w1t)
{
  __shared__ float t[32][33];
  transp_tile_s(t, w1, w1t, 768, 768, blockIdx.x % 24, blockIdx.x / 24);
}

// ---------- gemm1 + piggybacked independent prep ----------------------------
// blocks 0..767    : h1 = relu(seq @ w1t^T + b1)  (verbatim gemm16 body)
// blocks 768..1055 : w2t transpose
// blocks 1056..1343: Wct transpose (cw top/bot)
// block  1344      : Whead fragment pack + bh
__global__ __launch_bounds__(256) void gemm1_piggy_kernel(
    const float* __restrict__ seq, const __bf16* __restrict__ w1t,
    const float* __restrict__ b1, __bf16* __restrict__ h1b,
    const float* __restrict__ w2, __bf16* __restrict__ w2t,
    const float* __restrict__ cw, __bf16* __restrict__ Wct,
    const float* __restrict__ le_w, const float* __restrict__ le_b,
    const float* __restrict__ elh_w, const float* __restrict__ elh_b,
    const float* __restrict__ elt_w, const float* __restrict__ elt_b,
    const float* __restrict__ lgh_w, const float* __restrict__ lgh_b,
    const float* __restrict__ lgt_w, const float* __restrict__ lgt_b,
    _Float16* __restrict__ Whb, float* __restrict__ bh)
{
  __shared__ __align__(16) __bf16 As[2][16][136];   //  8.7 KB
  __shared__ __align__(16) __bf16 Bs[2][64][136];   // 34.8 KB
  const int bid = blockIdx.x;
  const int tid = threadIdx.x;

  if (bid >= 768) {
    if (bid < 1344) {                    // transposes (scratch aliased in As)
      float (*Ts)[33] = (float(*)[33])&As[0][0][0];
      int idx = bid - 768;
      if (idx < 288)
        transp_tile_s(Ts, w2, w2t, 768, 384, idx % 12, idx / 12);
      else if (idx < 432) {
        int i2 = idx - 288;
        transp_tile_s(Ts, cw, Wct, 384, 384, i2 % 12, i2 / 12);
      } else {
        int i2 = idx - 432;
        transp_tile_s(Ts, cw + 384 * 384, Wct + (size_t)384 * 384,
                      384, 384, i2 % 12, i2 / 12);
      }
    } else {                             // Whead pack
      for (int k = tid; k < 384; k += 256) {
        float row[16];
        row[0] = le_w[k * 2 + 0];
        row[1] = le_w[k * 2 + 1];
        #pragma unroll
        for (int c = 0; c < 3; ++c) {
          row[2 + c]  = elh_w[k * 3 + c];
          row[5 + c]  = elt_w[k * 3 + c];
          row[8 + c]  = lgh_w[k * 3 + c];
          row[11 + c] = lgt_w[k * 3 + c];
        }
        row[14] = 0.f; row[15] = 0.f;
        int kk = k >> 5, qd = (k >> 3) & 3, e = k & 7;
        size_t base = (size_t)((kk * 4 + qd) * 16) * 8 + e;
        #pragma unroll
        for (int col = 0; col < 16; ++col)
          Whb[base + col * 8] = (_Float16)row[col];
        if (k < 16) {
          float v = 0.f;
          if (k < 2) v = le_b[k];
          else if (k < 5) v = elh_b[k - 2];
          else if (k < 8) v = elt_b[k - 5];
          else if (k < 11) v = lgh_b[k - 8];
          else if (k < 14) v = lgt_b[k - 11];
          bh[k] = v;
        }
      }
    }
    return;
  }

  // ---- gemm1: K=768, N=768, verbatim R18 body; m0=(bid/12)*16, n0=(bid%12)*64
  const int m0 = (bid / 12) * 16, n0 = (bid % 12) * 64;
  const int lane = tid & 63, wave = tid >> 6;
  const int l15 = lane & 15, quad = lane >> 4, q8 = quad * 8;
  const int srA = tid >> 4, scA = (tid & 15) * 8;
  const int srB = tid >> 2, scB = (tid & 3) * 32;
  f32x4 acc = splat4(0.f);

  const __bf16* Bptr = w1t + (size_t)(n0 + srB) * 768 + scB;
  bf16x8 ra, rb0, rb1, rb2, rb3;
  auto loadA = [&](int ko) {
    const float* Af = seq + (size_t)(m0 + srA) * 768 + scA + ko;
    float4 f0 = *(const float4*)(Af);
    float4 f1 = *(const float4*)(Af + 4);
    bf16x8 o;
    o[0] = (__bf16)f0.x; o[1] = (__bf16)f0.y; o[2] = (__bf16)f0.z; o[3] = (__bf16)f0.w;
    o[4] = (__bf16)f1.x; o[5] = (__bf16)f1.y; o[6] = (__bf16)f1.z; o[7] = (__bf16)f1.w;
    ra = o;
  };
  auto loadB = [&](int ko) {
    rb0 = *(const bf16x8*)(Bptr + ko);
    rb1 = *(const bf16x8*)(Bptr + ko + 8);
    rb2 = *(const bf16x8*)(Bptr + ko + 16);
    rb3 = *(const bf16x8*)(Bptr + ko + 24);
  };
  loadA(0);
  loadB(0);

  int buf = 0;
  for (int it = 0; it < 6; ++it) {
    *(bf16x8*)&As[buf][srA][scA]      = ra;
    *(bf16x8*)&Bs[buf][srB][scB]      = rb0;
    *(bf16x8*)&Bs[buf][srB][scB + 8]  = rb1;
    *(bf16x8*)&Bs[buf][srB][scB + 16] = rb2;
    *(bf16x8*)&Bs[buf][srB][scB + 24] = rb3;
    __syncthreads();
    if (it + 1 < 6) {
      const int ko = (it + 1) * 128;
      loadA(ko);
      loadB(ko);
    }
    #pragma unroll
    for (int s = 0; s < 4; ++s) {
      bf16x8 a = *(const bf16x8*)&As[buf][l15][s * 32 + q8];
      bf16x8 b = *(const bf16x8*)&Bs[buf][wave * 16 + l15][s * 32 + q8];
      acc = __builtin_amdgcn_mfma_f32_16x16x32_bf16(a, b, acc, 0, 0, 0);
    }
    buf ^= 1;
  }
  const int col = n0 + wave * 16 + l15;
  const float bv = b1[col];
  #pragma unroll
  for (int r = 0; r < 4; ++r) {
    int row = m0 + quad * 4 + r;
    h1b[(size_t)row * 768 + col] = (__bf16)fmaxf(acc[r] + bv, 0.f);
  }
}

// ---------- bf16 MFMA GEMM, BM=16 x BN=64, 4 waves, BK=128 (R18/R20) --------
// OMODE: 1 = bf16 out, 2 = f16 out
template<int OMODE, bool RELU, bool BIAS_LHALF>
__global__ __launch_bounds__(256) void gemm16_kernel(
    const __bf16* __restrict__ Ain, const __bf16* __restrict__ Wt,
    const float* __restrict__ bias, void* __restrict__ out,
    int K, int N)
{
  __shared__ __align__(16) __bf16 As[2][16][136];
  __shared__ __align__(16) __bf16 Bs[2][64][136];
  const int tid = threadIdx.x;
  const int m0 = blockIdx.y * 16, n0 = blockIdx.x * 64;
  const int lane = tid & 63, wave = tid >> 6;
  const int l15 = lane & 15, quad = lane >> 4, q8 = quad * 8;
  const int srA = tid >> 4, scA = (tid & 15) * 8;
  const int srB = tid >> 2, scB = (tid & 3) * 32;
  f32x4 acc = splat4(0.f);

  const __bf16* Bptr = Wt + (size_t)(n0 + srB) * K + scB;
  bf16x8 ra, rb0, rb1, rb2, rb3;
  auto loadA = [&](int ko) {
    ra = *(const bf16x8*)(Ain + (size_t)(m0 + srA) * K + scA + ko);
  };
  auto loadB = [&](int ko) {
    rb0 = *(const bf16x8*)(Bptr + ko);
    rb1 = *(const bf16x8*)(Bptr + ko + 8);
    rb2 = *(const bf16x8*)(Bptr + ko + 16);
    rb3 = *(const bf16x8*)(Bptr + ko + 24);
  };
  loadA(0);
  loadB(0);

  const int nk = K >> 7;
  int buf = 0;
  for (int it = 0; it < nk; ++it) {
    *(bf16x8*)&As[buf][srA][scA]      = ra;
    *(bf16x8*)&Bs[buf][srB][scB]      = rb0;
    *(bf16x8*)&Bs[buf][srB][scB + 8]  = rb1;
    *(bf16x8*)&Bs[buf][srB][scB + 16] = rb2;
    *(bf16x8*)&Bs[buf][srB][scB + 24] = rb3;
    __syncthreads();
    if (it + 1 < nk) {
      const int ko = (it + 1) * 128;
      loadA(ko);
      loadB(ko);
    }
    #pragma unroll
    for (int s = 0; s < 4; ++s) {
      bf16x8 a = *(const bf16x8*)&As[buf][l15][s * 32 + q8];
      bf16x8 b = *(const bf16x8*)&Bs[buf][wave * 16 + l15][s * 32 + q8];
      acc = __builtin_amdgcn_mfma_f32_16x16x32_bf16(a, b, acc, 0, 0, 0);
    }
    buf ^= 1;
  }
  const int col = n0 + wave * 16 + l15;
  float bv = 0.f;
  if (BIAS_LHALF) { if (col < HD) bv = bias[col]; }
  else if (bias)  bv = bias[col];
  #pragma unroll
  for (int r = 0; r < 4; ++r) {
    int row = m0 + quad * 4 + r;
    float v = acc[r] + bv;
    if (RELU) v = fmaxf(v, 0.f);
    if constexpr (OMODE == 1) ((__bf16*)out)[(size_t)row * N + col] = (__bf16)v;
    else                      ((_Float16*)out)[(size_t)row * N + col] = (_Float16)v;
  }
}

// ---------- fused head: all-f16 datapath (R22/R23 proven) -------------------
__global__ __launch_bounds__(512, 8) void fused_head_tile(
    const _Float16* __restrict__ LR, const _Float16* __restrict__ Whb,
    const float* __restrict__ bh, float* __restrict__ out)
{
  __shared__ __align__(16) _Float16 Rsh[16][392];  // 12.5 KB
  __shared__ __align__(16) _Float16 Wl[6144];      // 12 KB
  int x = blockIdx.x;
  int b = 0;
  if (x >= 528) { b = 1; x -= 528; }
  int ti = 0;
  while (x >= 32 - ti) { x -= 32 - ti; ++ti; }
  const int tj = ti + x;
  const int i0 = ti * 16, j0 = tj * 16;
  const int tid = threadIdx.x;

  const _Float16* Rsrc = LR + (size_t)(b * S + j0) * (2 * HD) + HD;
  for (int t = tid; t < 768; t += 512) {           // 16 rows x 48 f16x8 chunks
    int row = t / 48, c8 = (t % 48) * 8;
    *(f16x8*)&Rsh[row][c8] = *(const f16x8*)(Rsrc + (size_t)row * (2 * HD) + c8);
  }
  for (int t = tid; t < 768; t += 512)
    ((f16x8*)Wl)[t] = ((const f16x8*)Whb)[t];
  const int lane = tid & 63, col = lane & 15, quad = lane >> 4;
  const float bhv = bh[col];
  __syncthreads();

  const int wave = tid >> 6;            // 0..7; wave owns i-rows i, i+1
  const int i = i0 + wave * 2;
  const _Float16* L0 = LR + (size_t)(b * S + i) * (2 * HD);
  const _Float16* L1 = L0 + 2 * HD;
  f32x4 acc0 = splat4(0.f), acc1 = splat4(0.f);
  const int q8 = quad * 8;

  f16x8 a = *(const f16x8*)(L0 + q8);
  f16x8 c = *(const f16x8*)(L1 + q8);
  f16x8 r = *(const f16x8*)&Rsh[col][q8];

  #pragma unroll
  for (int kk = 0; kk < 12; ++kk) {
    f16x8 na, nc, nr;
    if (kk < 11) {
      const int kb1 = (kk + 1) * 32 + q8;
      na = *(const f16x8*)(L0 + kb1);
      nc = *(const f16x8*)(L1 + kb1);
      nr = *(const f16x8*)&Rsh[col][kb1];
    }
    f16x8 w = *(const f16x8*)&Wl[(size_t)((kk * 4 + quad) * 16 + col) * 8];
    f16x8 af = tanh8_from_x(a + r);
    acc0 = __builtin_amdgcn_mfma_f32_16x16x32_f16(af, w, acc0, 0, 0, 0);
    f16x8 ag = tanh8_from_x(c + r);
    acc1 = __builtin_amdgcn_mfma_f32_16x16x32_f16(ag, w, acc1, 0, 0, 0);
    a = na; c = nc; r = nr;
  }
  if (col < NOUT) {
    #pragma unroll
    for (int ii = 0; ii < 2; ++ii) {
      const int ic = i + ii;
      const f32x4 acc = ii ? acc1 : acc0;
      const size_t pbase = (size_t)b * NPAIR + (size_t)ic * S - ((size_t)ic * (ic - 1)) / 2;
      #pragma unroll
      for (int rr = 0; rr < 4; ++rr) {
        int j = j0 + quad * 4 + rr;
        if (j >= ic)
          out[(pbase + (size_t)(j - ic)) * NOUT + col] = acc[rr] + bhv;
      }
    }
  }
}

extern "C" void kernel_launch(void* const* d_in, const int* in_sizes, int n_in,
                              void* d_out, int out_size, void* d_ws, size_t ws_size,
                              hipStream_t stream) {
  const float* seq   = (const float*)d_in[0];
  const float* w1    = (const float*)d_in[1];
  const float* b1    = (const float*)d_in[2];
  const float* w2    = (const float*)d_in[3];
  const float* b2    = (const float*)d_in[4];
  const float* cw    = (const float*)d_in[5];
  const float* cbp   = (const float*)d_in[6];
  const float* le_w  = (const float*)d_in[7];
  const float* le_b  = (const float*)d_in[8];
  const float* elh_w = (const float*)d_in[9];
  const float* elh_b = (const float*)d_in[10];
  const float* elt_w = (const float*)d_in[11];
  const float* elt_b = (const float*)d_in[12];
  const float* lgh_w = (const float*)d_in[13];
  const float* lgh_b = (const float*)d_in[14];
  const float* lgt_w = (const float*)d_in[15];
  const float* lgt_b = (const float*)d_in[16];

  char* p = (char*)d_ws;
  _Float16* LRb = (_Float16*)p;              // 1,572,864 B  [L|R] f16, +cb on L
  __bf16*   h1b = (__bf16*)(p + 1572864);    // 1,572,864 B
  __bf16*   h2b = (__bf16*)(p + 3145728);    //   786,432 B
  __bf16*   w1t = (__bf16*)(p + 3932160);    // 1,179,648 B
  __bf16*   w2t = (__bf16*)(p + 5111808);    //   589,824 B
  __bf16*   Wct = (__bf16*)(p + 5701632);    //   589,824 B
  float*    bh  = (float*)(p + 6291456);     //        64 B
  _Float16* Whb = (_Float16*)(p + 6291520);  //    12,288 B

  // 1) w1 transpose (gemm1's only dependency)
  prep1_kernel<<<576, 256, 0, stream>>>(w1, w1t);
  // 2) gemm1 + piggybacked w2t/Wct/Whead prep (independent of gemm1)
  gemm1_piggy_kernel<<<1345, 256, 0, stream>>>(
      seq, w1t, b1, h1b, w2, w2t, cw, Wct,
      le_w, le_b, elh_w, elh_b, elt_w, elt_b,
      lgh_w, lgh_b, lgt_w, lgt_b, Whb, bh);
  // 3) h2 = relu(h1 @ w2 + b2)
  gemm16_kernel<1, true, false><<<dim3(6, 64), 256, 0, stream>>>(
      h1b, w2t, b2, h2b, 768, 384);
  // 4) LR = h2 @ [w_top|w_bot] (+cb on L), f16 out
  gemm16_kernel<2, false, true><<<dim3(12, 64), 256, 0, stream>>>(
      h2b, Wct, cbp, LRb, 384, 768);
  // 5) fused pair-head
  fused_head_tile<<<1056, 512, 0, stream>>>(LRb, Whb, bh, (float*)d_out);
}

// Round 25
// 47.426 us; speedup vs baseline: 1.0165x; 1.0165x over previous
//
#include <hip/hip_runtime.h>
#include <hip/hip_bf16.h>

#define S 512
#define HD 384
#define NPAIR 131328   // S*(S+1)/2
#define NOUT 14

typedef __bf16 bf16x8 __attribute__((ext_vector_type(8)));
typedef _Float16 f16x8 __attribute__((ext_vector_type(8)));
typedef float f32x4 __attribute__((ext_vector_type(4)));

__device__ __forceinline__ f32x4 splat4(float v) { return f32x4{v, v, v, v}; }
__device__ __forceinline__ f16x8 splat8h(float v) {
  _Float16 h = (_Float16)v;
  return f16x8{h, h, h, h, h, h, h, h};
}

// tanh poly, deg-5 odd fit (same coeffs since R10). x already f16.
__device__ __forceinline__ f16x8 tanh8_from_x(f16x8 x) {
  f16x8 u = x * x;
  f16x8 p = __builtin_elementwise_fma(u, splat8h(0.065750f), splat8h(-0.303330f));
  p = __builtin_elementwise_fma(u, p, splat8h(0.997245f));
  return x * p;
}

// ---------- prep: weight transposes + head-weight fragment pack -------------
__device__ __forceinline__ void transp_tile(
    const float* __restrict__ src, __bf16* __restrict__ dst,
    int R, int C, int bx, int by)
{
  __shared__ float t[32][33];
  const int tx = threadIdx.x & 31, ty = threadIdx.x >> 5;  // 32 x 8
  const int c = bx * 32 + tx;
  #pragma unroll
  for (int p = 0; p < 4; ++p) {
    int r = by * 32 + ty + p * 8;
    t[ty + p * 8][tx] = src[(size_t)r * C + c];
  }
  __syncthreads();
  #pragma unroll
  for (int p = 0; p < 4; ++p) {
    int cc = bx * 32 + ty + p * 8;
    int rr = by * 32 + tx;
    dst[(size_t)cc * R + rr] = (__bf16)t[tx][ty + p * 8];
  }
}

__global__ __launch_bounds__(256) void prep_all_kernel(
    const float* __restrict__ w1, __bf16* __restrict__ w1t,
    const float* __restrict__ w2, __bf16* __restrict__ w2t,
    const float* __restrict__ cw, __bf16* __restrict__ Wct,
    const float* __restrict__ le_w, const float* __restrict__ le_b,
    const float* __restrict__ elh_w, const float* __restrict__ elh_b,
    const float* __restrict__ elt_w, const float* __restrict__ elt_b,
    const float* __restrict__ lgh_w, const float* __restrict__ lgh_b,
    const float* __restrict__ lgt_w, const float* __restrict__ lgt_b,
    _Float16* __restrict__ Whb, float* __restrict__ bh)
{
  const int bid = blockIdx.x;
  if (bid < 576) {
    transp_tile(w1, w1t, 768, 768, bid % 24, bid / 24);
  } else if (bid < 864) {
    int idx = bid - 576;
    transp_tile(w2, w2t, 768, 384, idx % 12, idx / 12);
  } else if (bid < 1008) {
    int idx = bid - 864;
    transp_tile(cw, Wct, 384, 384, idx % 12, idx / 12);
  } else if (bid < 1152) {
    int idx = bid - 1008;
    transp_tile(cw + 384 * 384, Wct + (size_t)384 * 384, 384, 384, idx % 12, idx / 12);
  } else {
    for (int k = threadIdx.x; k < 384; k += 256) {
      float row[16];
      row[0] = le_w[k * 2 + 0];
      row[1] = le_w[k * 2 + 1];
      #pragma unroll
      for (int c = 0; c < 3; ++c) {
        row[2 + c]  = elh_w[k * 3 + c];
        row[5 + c]  = elt_w[k * 3 + c];
        row[8 + c]  = lgh_w[k * 3 + c];
        row[11 + c] = lgt_w[k * 3 + c];
      }
      row[14] = 0.f; row[15] = 0.f;
      int kk = k >> 5, quad = (k >> 3) & 3, e = k & 7;
      size_t base = (size_t)((kk * 4 + quad) * 16) * 8 + e;
      #pragma unroll
      for (int col = 0; col < 16; ++col)
        Whb[base + col * 8] = (_Float16)row[col];
      if (k < 16) {
        float v = 0.f;
        if (k < 2) v = le_b[k];
        else if (k < 5) v = elh_b[k - 2];
        else if (k < 8) v = elt_b[k - 5];
        else if (k < 11) v = lgh_b[k - 8];
        else if (k < 14) v = lgt_b[k - 11];
        bh[k] = v;
      }
    }
  }
}

// ---------- bf16 MFMA GEMM, BM=16 x BN=64, 4 waves, BK=128 ------------------
// OMODE: 0 = f32 out, 1 = bf16 out, 2 = f16 out
template<bool CVT_A, int OMODE, bool RELU, bool BIAS_LHALF>
__global__ __launch_bounds__(256) void gemm16_kernel(
    const void* __restrict__ Ain, const __bf16* __restrict__ Wt,
    const float* __restrict__ bias, void* __restrict__ out,
    int K, int N)
{
  __shared__ __align__(16) __bf16 As[2][16][136];   //  8.7 KB
  __shared__ __align__(16) __bf16 Bs[2][64][136];   // 34.8 KB
  const int tid = threadIdx.x;
  const int m0 = blockIdx.y * 16, n0 = blockIdx.x * 64;
  const int lane = tid & 63, wave = tid >> 6;
  const int l15 = lane & 15, quad = lane >> 4, q8 = quad * 8;
  const int srA = tid >> 4, scA = (tid & 15) * 8;   // 16 rows x 16 thr x 8 bf16
  const int srB = tid >> 2, scB = (tid & 3) * 32;   // 64 rows x 4 thr x 32 bf16
  f32x4 acc = splat4(0.f);

  const __bf16* Bptr = Wt + (size_t)(n0 + srB) * K + scB;
  bf16x8 ra, rb0, rb1, rb2, rb3;
  auto loadA = [&](int ko) {
    if constexpr (CVT_A) {
      const float* Af = (const float*)Ain + (size_t)(m0 + srA) * K + scA + ko;
      float4 f0 = *(const float4*)(Af);
      float4 f1 = *(const float4*)(Af + 4);
      bf16x8 o;
      o[0] = (__bf16)f0.x; o[1] = (__bf16)f0.y; o[2] = (__bf16)f0.z; o[3] = (__bf16)f0.w;
      o[4] = (__bf16)f1.x; o[5] = (__bf16)f1.y; o[6] = (__bf16)f1.z; o[7] = (__bf16)f1.w;
      ra = o;
    } else {
      ra = *(const bf16x8*)((const __bf16*)Ain + (size_t)(m0 + srA) * K + scA + ko);
    }
  };
  auto loadB = [&](int ko) {
    rb0 = *(const bf16x8*)(Bptr + ko);
    rb1 = *(const bf16x8*)(Bptr + ko + 8);
    rb2 = *(const bf16x8*)(Bptr + ko + 16);
    rb3 = *(const bf16x8*)(Bptr + ko + 24);
  };
  loadA(0);
  loadB(0);

  const int nk = K >> 7;   // K multiple of 128
  int buf = 0;
  for (int it = 0; it < nk; ++it) {
    *(bf16x8*)&As[buf][srA][scA]      = ra;
    *(bf16x8*)&Bs[buf][srB][scB]      = rb0;
    *(bf16x8*)&Bs[buf][srB][scB + 8]  = rb1;
    *(bf16x8*)&Bs[buf][srB][scB + 16] = rb2;
    *(bf16x8*)&Bs[buf][srB][scB + 24] = rb3;
    __syncthreads();
    if (it + 1 < nk) {
      const int ko = (it + 1) * 128;
      loadA(ko);
      loadB(ko);
    }
    #pragma unroll
    for (int s = 0; s < 4; ++s) {
      bf16x8 a = *(const bf16x8*)&As[buf][l15][s * 32 + q8];
      bf16x8 b = *(const bf16x8*)&Bs[buf][wave * 16 + l15][s * 32 + q8];
      acc = __builtin_amdgcn_mfma_f32_16x16x32_bf16(a, b, acc, 0, 0, 0);
    }
    buf ^= 1;
  }
  const int col = n0 + wave * 16 + l15;
  float bv = 0.f;
  if (BIAS_LHALF) { if (col < HD) bv = bias[col]; }
  else if (bias)  bv = bias[col];
  #pragma unroll
  for (int r = 0; r < 4; ++r) {
    int row = m0 + quad * 4 + r;
    float v = acc[r] + bv;
    if (RELU) v = fmaxf(v, 0.f);
    if constexpr (OMODE == 1)      ((__bf16*)out)[(size_t)row * N + col] = (__bf16)v;
    else if constexpr (OMODE == 2) ((_Float16*)out)[(size_t)row * N + col] = (_Float16)v;
    else                           ((float*)out)[(size_t)row * N + col] = v;
  }
}

// ---------- fused head: all-f16 datapath (R22/R23 proven) -------------------
__global__ __launch_bounds__(512, 8) void fused_head_tile(
    const _Float16* __restrict__ LR, const _Float16* __restrict__ Whb,
    const float* __restrict__ bh, float* __restrict__ out)
{
  __shared__ __align__(16) _Float16 Rsh[16][392];  // 12.5 KB
  __shared__ __align__(16) _Float16 Wl[6144];      // 12 KB
  int x = blockIdx.x;
  int b = 0;
  if (x >= 528) { b = 1; x -= 528; }
  int ti = 0;
  while (x >= 32 - ti) { x -= 32 - ti; ++ti; }
  const int tj = ti + x;
  const int i0 = ti * 16, j0 = tj * 16;
  const int tid = threadIdx.x;

  const _Float16* Rsrc = LR + (size_t)(b * S + j0) * (2 * HD) + HD;
  for (int t = tid; t < 768; t += 512) {           // 16 rows x 48 f16x8 chunks
    int row = t / 48, c8 = (t % 48) * 8;
    *(f16x8*)&Rsh[row][c8] = *(const f16x8*)(Rsrc + (size_t)row * (2 * HD) + c8);
  }
  for (int t = tid; t < 768; t += 512)
    ((f16x8*)Wl)[t] = ((const f16x8*)Whb)[t];
  const int lane = tid & 63, col = lane & 15, quad = lane >> 4;
  const float bhv = bh[col];
  __syncthreads();

  const int wave = tid >> 6;            // 0..7; wave owns i-rows i, i+1
  const int i = i0 + wave * 2;
  const _Float16* L0 = LR + (size_t)(b * S + i) * (2 * HD);
  const _Float16* L1 = L0 + 2 * HD;
  f32x4 acc0 = splat4(0.f), acc1 = splat4(0.f);
  const int q8 = quad * 8;

  // depth-1 prefetch on L (global) and R (LDS)
  f16x8 a = *(const f16x8*)(L0 + q8);
  f16x8 c = *(const f16x8*)(L1 + q8);
  f16x8 r = *(const f16x8*)&Rsh[col][q8];

  #pragma unroll
  for (int kk = 0; kk < 12; ++kk) {
    f16x8 na, nc, nr;
    if (kk < 11) {
      const int kb1 = (kk + 1) * 32 + q8;
      na = *(const f16x8*)(L0 + kb1);
      nc = *(const f16x8*)(L1 + kb1);
      nr = *(const f16x8*)&Rsh[col][kb1];
    }
    f16x8 w = *(const f16x8*)&Wl[(size_t)((kk * 4 + quad) * 16 + col) * 8];
    f16x8 af = tanh8_from_x(a + r);
    acc0 = __builtin_amdgcn_mfma_f32_16x16x32_f16(af, w, acc0, 0, 0, 0);
    f16x8 ag = tanh8_from_x(c + r);
    acc1 = __builtin_amdgcn_mfma_f32_16x16x32_f16(ag, w, acc1, 0, 0, 0);
    a = na; c = nc; r = nr;
  }
  if (col < NOUT) {
    #pragma unroll
    for (int ii = 0; ii < 2; ++ii) {
      const int ic = i + ii;
      const f32x4 acc = ii ? acc1 : acc0;
      const size_t pbase = (size_t)b * NPAIR + (size_t)ic * S - ((size_t)ic * (ic - 1)) / 2;
      #pragma unroll
      for (int rr = 0; rr < 4; ++rr) {
        int j = j0 + quad * 4 + rr;
        if (j >= ic)
          out[(pbase + (size_t)(j - ic)) * NOUT + col] = acc[rr] + bhv;
      }
    }
  }
}

extern "C" void kernel_launch(void* const* d_in, const int* in_sizes, int n_in,
                              void* d_out, int out_size, void* d_ws, size_t ws_size,
                              hipStream_t stream) {
  const float* seq   = (const float*)d_in[0];
  const float* w1    = (const float*)d_in[1];
  const float* b1    = (const float*)d_in[2];
  const float* w2    = (const float*)d_in[3];
  const float* b2    = (const float*)d_in[4];
  const float* cw    = (const float*)d_in[5];
  const float* cbp   = (const float*)d_in[6];
  const float* le_w  = (const float*)d_in[7];
  const float* le_b  = (const float*)d_in[8];
  const float* elh_w = (const float*)d_in[9];
  const float* elh_b = (const float*)d_in[10];
  const float* elt_w = (const float*)d_in[11];
  const float* elt_b = (const float*)d_in[12];
  const float* lgh_w = (const float*)d_in[13];
  const float* lgh_b = (const float*)d_in[14];
  const float* lgt_w = (const float*)d_in[15];
  const float* lgt_b = (const float*)d_in[16];

  char* p = (char*)d_ws;
  _Float16* LRb = (_Float16*)p;              // 1,572,864 B  [L|R] f16, +cb on L
  __bf16*   h1b = (__bf16*)(p + 1572864);    // 1,572,864 B
  __bf16*   h2b = (__bf16*)(p + 3145728);    //   786,432 B
  __bf16*   w1t = (__bf16*)(p + 3932160);    // 1,179,648 B
  __bf16*   w2t = (__bf16*)(p + 5111808);    //   589,824 B
  __bf16*   Wct = (__bf16*)(p + 5701632);    //   589,824 B
  float*    bh  = (float*)(p + 6291456);     //        64 B
  _Float16* Whb = (_Float16*)(p + 6291520);  //    12,288 B

  prep_all_kernel<<<1153, 256, 0, stream>>>(
      w1, w1t, w2, w2t, cw, Wct,
      le_w, le_b, elh_w, elh_b, elt_w, elt_b,
      lgh_w, lgh_b, lgt_w, lgt_b, Whb, bh);
  // h1 = relu(seq @ w1 + b1); 768 blocks
  gemm16_kernel<true, 1, true, false><<<dim3(12, 64), 256, 0, stream>>>(
      seq, w1t, b1, h1b, 768, 768);
  // h2 = relu(h1 @ w2 + b2); 384 blocks
  gemm16_kernel<false, 1, true, false><<<dim3(6, 64), 256, 0, stream>>>(
      h1b, w2t, b2, h2b, 768, 384);
  // LR = h2 @ [w_top|w_bot] (+cb on L), f16 out; 768 blocks
  gemm16_kernel<false, 2, false, true><<<dim3(12, 64), 256, 0, stream>>>(
      h2b, Wct, cbp, LRb, 384, 768);
  fused_head_tile<<<1056, 512, 0, stream>>>(LRb, Whb, bh, (float*)d_out);
}